// Round 3
// baseline (311.354 us; speedup 1.0000x reference)
//
#include <hip/hip_runtime.h>

// GAT attention weights (heads=1) for two block-diagonal graphs.
// Output = softmax-by-dst of leakyrelu(a_s[src]+a_d[dst]) over N*N edges.
//
// R8: MLP (memory-level-parallelism) fix. Evidence from R5-R7: four edge
// kernel variants with different op mixes (3 LDS vs 1 LDS vs TA gather,
// 8 vs 74 MB writes, with/without exp) ALL ran ~97 us, each reading
// exactly 134 MB of coalesced streams = 1.38 TB/s = 2.25 B/cyc/CU (vs
// 10 B/cyc streaming ceiling, m13). VGPR_Count was 16: the compiler
// scheduled each iteration's global loads AFTER the previous iteration's
// LDS atomics -> ~1.5 loads in flight/wave. Little's law at ~500 cyc
// latency gives exactly 2.2 B/cyc. The kernels are latency x MLP bound.
//
// Fix: explicit load phase (all 16 int4 loads issued to registers before
// any LDS op) + process phase. __launch_bounds__(1024,4) -> 128-VGPR cap,
// 1 block/CU, 16 waves x 16 outstanding x 16 B = 4 KB/CU in flight.
//
// Algorithm (unchanged from R7):
//   exp(lrelu(as+ad)) = e^as * e^ad          (as+ad > 0)
//                     = e^{.2as} * e^{.2ad}  (else)
// Pass 1 streams val = branch ? +e^as : -e^{.2as} into d_out and
// accumulates split sums s1,s2 per dst (LDS), folded with e^{ad} into one
// partial per node. Pass 2 reads val + dst, one ds_read_b64 of
// {u=e^ad*inv, v=e^{.2ad}*inv}: alpha = val>0 ? val*u : (-val)*v.
//
// No segment-max: logits bounded ~7.2 -> exp <= ~1400, safe in fp32.

#define NNODES 4096
#define NSEG   8192
#define NEG_SLOPE 0.2f
#define EK_TPB 1024
#define EK_QPB 8192          // int4 quads per edge-kernel block = 32768 edges

__global__ void k1_wvec(const float* __restrict__ W,
                        const float* __restrict__ att_src,
                        const float* __restrict__ att_dst,
                        float* __restrict__ wvs, float* __restrict__ wvd) {
    int f = threadIdx.x;
    const float* row = W + f * 128;
    float s = 0.f, d = 0.f;
    #pragma unroll 8
    for (int j = 0; j < 128; ++j) {
        float w = row[j];
        s += w * att_src[j];
        d += w * att_dst[j];
    }
    wvs[f] = s; wvd[f] = d;
}

// Per-node logits + precomputed tables:
//   espair[n] = {e^{a_s}, e^{0.2 a_s}}   (pass-1 src operand, one b64 read)
//   wtab[n]   = e^{-a_d}                 (pass-1 branch threshold: p > w)
//   a_d[n]                               (kA epilogue / k4b combine)
__global__ void k2_logits(const float* __restrict__ x1, const float* __restrict__ x2,
                          const float* __restrict__ wvs, const float* __restrict__ wvd,
                          float* __restrict__ a_d, float2* __restrict__ espair,
                          float* __restrict__ wtab) {
    int wave = blockIdx.x * 4 + (threadIdx.x >> 6);
    int lane = threadIdx.x & 63;
    const float* xrow = (wave < NNODES) ? (x1 + (size_t)wave * 256)
                                        : (x2 + (size_t)(wave - NNODES) * 256);
    float4 xv  = ((const float4*)xrow)[lane];
    float4 wsv = ((const float4*)wvs)[lane];
    float4 wdv = ((const float4*)wvd)[lane];
    float ps = xv.x*wsv.x + xv.y*wsv.y + xv.z*wsv.z + xv.w*wsv.w;
    float pd = xv.x*wdv.x + xv.y*wdv.y + xv.z*wdv.z + xv.w*wdv.w;
    #pragma unroll
    for (int o = 32; o > 0; o >>= 1) {
        ps += __shfl_down(ps, o);
        pd += __shfl_down(pd, o);
    }
    if (lane == 0) {
        a_d[wave]    = pd;
        espair[wave] = make_float2(__expf(ps), __expf(NEG_SLOPE * ps));
        wtab[wave]   = __expf(-pd);
    }
}

// Pass 1: load phase issues all 16 int4 index loads (64 VGPRs in flight),
// THEN the LDS process phase. Streams signed val to d_out. Epilogue folds
// {s1,s2} into a single per-block partial denominator.
__global__ __launch_bounds__(EK_TPB, 4) void kA_denom(
        const int* __restrict__ ei1, const int* __restrict__ ei2,
        const float2* __restrict__ espair, const float* __restrict__ wtab,
        const float* __restrict__ a_d,
        float* __restrict__ partials, float* __restrict__ out,
        int E1, int g1_blocks) {
    __shared__ float2 les[NNODES];           // 32 KB {e^as, e^.2as}
    __shared__ float  lw[NNODES];            // 16 KB e^{-ad}
    __shared__ float  s12[2 * NNODES];       // 32 KB split sums (80 KB total)
    int t = threadIdx.x;
    int b = blockIdx.x;
    const int* sp; int qbase, nodeoff, outq;
    if (b < g1_blocks) { sp = ei1; qbase = b * EK_QPB; nodeoff = 0; outq = qbase; }
    else { sp = ei2; qbase = (b - g1_blocks) * EK_QPB; nodeoff = NNODES; outq = E1/4 + qbase; }
    const int4* s4 = (const int4*)sp;
    const int4* d4 = (const int4*)(sp + E1);

    // ---- load phase: all index loads in flight before any LDS op ----
    int4 sv[8], dv[8];
    #pragma unroll
    for (int k = 0; k < 8; ++k) {
        int q = qbase + (k << 10) + t;
        sv[k] = s4[q];
        dv[k] = d4[q];
    }

    {   // stage tables: les = 2048 float4, lw = 1024 float4, s12 = 2048 float4
        float4* lesv = (float4*)les;
        const float4* gesv = (const float4*)(espair + nodeoff);
        lesv[t] = gesv[t]; lesv[t + 1024] = gesv[t + 1024];
        ((float4*)lw)[t] = ((const float4*)(wtab + nodeoff))[t];
        float4* zv = (float4*)s12;
        zv[t] = make_float4(0.f,0.f,0.f,0.f);
        zv[t + 1024] = make_float4(0.f,0.f,0.f,0.f);
    }
    __syncthreads();

    // ---- process phase: LDS only (plus the free val stream-out) ----
    float4* out4 = (float4*)out;
    #pragma unroll
    for (int k = 0; k < 8; ++k) {
        float2 e0 = les[sv[k].x], e1 = les[sv[k].y], e2 = les[sv[k].z], e3 = les[sv[k].w];
        float  w0 = lw[dv[k].x],  w1 = lw[dv[k].y],  w2 = lw[dv[k].z],  w3 = lw[dv[k].w];
        bool p0 = e0.x > w0, p1 = e1.x > w1, p2 = e2.x > w2, p3 = e3.x > w3;
        atomicAdd(&s12[dv[k].x + (p0 ? 0 : NNODES)], p0 ? e0.x : e0.y);
        atomicAdd(&s12[dv[k].y + (p1 ? 0 : NNODES)], p1 ? e1.x : e1.y);
        atomicAdd(&s12[dv[k].z + (p2 ? 0 : NNODES)], p2 ? e2.x : e2.y);
        atomicAdd(&s12[dv[k].w + (p3 ? 0 : NNODES)], p3 ? e3.x : e3.y);
        out4[outq + (k << 10) + t] = make_float4(p0 ? e0.x : -e0.y,
                                                 p1 ? e1.x : -e1.y,
                                                 p2 ? e2.x : -e2.y,
                                                 p3 ? e3.x : -e3.y);
    }
    __syncthreads();

    // partial_denom[n] = e^{ad}*s1[n] + e^{0.2 ad}*s2[n]  (linear in s1,s2,
    // so per-block combine is exact); keeps partials at 8 MB total.
    float4 ad4 = ((const float4*)(a_d + nodeoff))[t];
    int n = 4 * t;
    float4 r;
    r.x = __expf(ad4.x) * s12[n+0] + __expf(NEG_SLOPE * ad4.x) * s12[n+0+NNODES];
    r.y = __expf(ad4.y) * s12[n+1] + __expf(NEG_SLOPE * ad4.y) * s12[n+1+NNODES];
    r.z = __expf(ad4.z) * s12[n+2] + __expf(NEG_SLOPE * ad4.z) * s12[n+2+NNODES];
    r.w = __expf(ad4.w) * s12[n+3] + __expf(NEG_SLOPE * ad4.w) * s12[n+3+NNODES];
    ((float4*)(partials + (size_t)b * NNODES))[t] = r;
}

__global__ void k4a_reduce(const float* __restrict__ partials,
                           float* __restrict__ partials2, int g1_blocks) {
    int tid = blockIdx.x * blockDim.x + threadIdx.x;
    int c  = tid >> 13;
    int sg = tid & (NSEG - 1);
    int bpc = g1_blocks >> 3;
    int b0 = ((sg < NNODES) ? 0 : g1_blocks) + c * bpc;
    int col = sg & (NNODES - 1);
    float s = 0.f;
    #pragma unroll 8
    for (int j = 0; j < bpc; ++j)
        s += partials[(size_t)(b0 + j) * NNODES + col];
    partials2[tid] = s;
}

__global__ void k4b_inv(const float* __restrict__ partials2,
                        const float* __restrict__ a_d,
                        float2* __restrict__ uv) {
    int sg = blockIdx.x * blockDim.x + threadIdx.x;
    float s = 0.f;
    #pragma unroll
    for (int c = 0; c < 8; ++c) s += partials2[c * NSEG + sg];
    float inv = 1.0f / s;
    float ad = a_d[sg];
    uv[sg] = make_float2(__expf(ad) * inv, __expf(NEG_SLOPE * ad) * inv);
}

// Pass 2: load phase (dv[8] + val[8] in flight), then ONE ds_read_b64 per
// edge. val sign carries the pass-1 branch.
__global__ __launch_bounds__(EK_TPB, 4) void kB_alpha(
        const int* __restrict__ ei1, const int* __restrict__ ei2,
        const float2* __restrict__ uv,
        float* __restrict__ out, int E1, int g1_blocks) {
    __shared__ float2 luv[NNODES];           // 32 KB
    int t = threadIdx.x;
    int b = blockIdx.x;
    const int* sp; int qbase, outq;
    const float2* uvg;
    if (b < g1_blocks) { sp = ei1; qbase = b * EK_QPB; uvg = uv; outq = qbase; }
    else { sp = ei2; qbase = (b - g1_blocks) * EK_QPB; uvg = uv + NNODES; outq = E1/4 + qbase; }
    const int4* d4 = (const int4*)(sp + E1);
    float4* out4 = (float4*)out;

    // ---- load phase: dst indices + vals all in flight ----
    int4   dv[8];
    float4 va[8];
    #pragma unroll
    for (int k = 0; k < 8; ++k) {
        int q = qbase + (k << 10) + t;
        dv[k] = d4[q];
        va[k] = out4[outq + (k << 10) + t];
    }

    float4* luvv = (float4*)luv;
    const float4* guv = (const float4*)uvg;
    luvv[t] = guv[t]; luvv[t + 1024] = guv[t + 1024];
    __syncthreads();

    #pragma unroll
    for (int k = 0; k < 8; ++k) {
        float2 u0 = luv[dv[k].x], u1 = luv[dv[k].y], u2 = luv[dv[k].z], u3 = luv[dv[k].w];
        float4 val = va[k];
        val.x = (val.x > 0.f) ? val.x * u0.x : (-val.x) * u0.y;
        val.y = (val.y > 0.f) ? val.y * u1.x : (-val.y) * u1.y;
        val.z = (val.z > 0.f) ? val.z * u2.x : (-val.z) * u2.y;
        val.w = (val.w > 0.f) ? val.w * u3.x : (-val.w) * u3.y;
        out4[outq + (k << 10) + t] = val;
    }
}

extern "C" void kernel_launch(void* const* d_in, const int* in_sizes, int n_in,
                              void* d_out, int out_size, void* d_ws, size_t ws_size,
                              hipStream_t stream) {
    const float* x1      = (const float*)d_in[0];
    const float* x2      = (const float*)d_in[1];
    const int*   ei1     = (const int*)d_in[2];
    const int*   ei2     = (const int*)d_in[3];
    const float* W       = (const float*)d_in[4];
    const float* att_src = (const float*)d_in[5];
    const float* att_dst = (const float*)d_in[6];
    float* out = (float*)d_out;

    const int E1 = in_sizes[2] / 2;          // 8388608 edges per graph

    float* wsf       = (float*)d_ws;
    float* wvs       = wsf;                  // 256
    float* wvd       = wsf + 256;            // 256
    float* a_d       = wsf + 512;            // 8192
    float2* espair   = (float2*)(wsf + 512 + NSEG);        // 8192 float2 (16384 f)
    float* wtab      = wsf + 512 + NSEG + 2*NSEG;          // 8192
    float2* uv       = (float2*)(wsf + 512 + 4*NSEG);      // 8192 float2 (16384 f)
    float* partials2 = wsf + 65536;          // 8*8192 = 65536 floats
    float* partials  = wsf + 131072;         // 512*4096 floats (8 MB)

    hipLaunchKernelGGL(k1_wvec, dim3(1), dim3(256), 0, stream,
                       W, att_src, att_dst, wvs, wvd);
    hipLaunchKernelGGL(k2_logits, dim3(2 * NNODES / 4), dim3(256), 0, stream,
                       x1, x2, wvs, wvd, a_d, espair, wtab);

    int g1b = (E1 / 4) / EK_QPB;             // 256 blocks per graph half
    hipLaunchKernelGGL(kA_denom, dim3(2 * g1b), dim3(EK_TPB), 0, stream,
                       ei1, ei2, espair, wtab, a_d, partials, out, E1, g1b);
    hipLaunchKernelGGL(k4a_reduce, dim3(8 * NSEG / 256), dim3(256), 0, stream,
                       partials, partials2, g1b);
    hipLaunchKernelGGL(k4b_inv, dim3(NSEG / 256), dim3(256), 0, stream,
                       partials2, a_d, uv);
    hipLaunchKernelGGL(kB_alpha, dim3(2 * g1b), dim3(EK_TPB), 0, stream,
                       ei1, ei2, uv, out, E1, g1b);
}

// Round 4
// 278.329 us; speedup vs baseline: 1.1187x; 1.1187x over previous
//
#include <hip/hip_runtime.h>

// GAT attention weights (heads=1) for two block-diagonal graphs.
// Output = softmax-by-dst of leakyrelu(a_s[src]+a_d[dst]) over N*N edges.
//
// R9: MLP fix, corrected for the barrier-drain bug that sank R8.
// Evidence R5-R7: all edge-kernel variants read 134 MB coalesced at
// 1.38 TB/s (2.25 B/cyc/CU) regardless of op mix; VGPR=16 -> ~1.5 loads
// in flight/wave (compiler won't hoist loads above atomicAdd). R8 put the
// load phase BEFORE __syncthreads -> hipcc's mandatory vmcnt(0) drain at
// the barrier serialized load/process phases entirely (98->142 us).
// R9 places the load phase AFTER the staging barrier and BEFORE the first
// atomic: compiler can't sink loads below atomics, so all 16 int4 loads
// stay in flight and uses get fine-grained vmcnt(N) waits.
//
// Algorithm (unchanged from R7):
//   exp(lrelu(as+ad)) = e^as * e^ad          (as+ad > 0)
//                     = e^{.2as} * e^{.2ad}  (else)
// Pass 1 streams val = branch ? +e^as : -e^{.2as} into d_out and
// accumulates split sums s1,s2 per dst (LDS), folded with e^{ad} into one
// partial per node. Pass 2 reads val + dst, one ds_read_b64 of
// {u=e^ad*inv, v=e^{.2ad}*inv}: alpha = val>0 ? val*u : (-val)*v.
//
// No segment-max: logits bounded ~7.2 -> exp <= ~1400, safe in fp32.

#define NNODES 4096
#define NSEG   8192
#define NEG_SLOPE 0.2f
#define EK_TPB 1024
#define EK_QPB 8192          // int4 quads per edge-kernel block = 32768 edges

__global__ void k1_wvec(const float* __restrict__ W,
                        const float* __restrict__ att_src,
                        const float* __restrict__ att_dst,
                        float* __restrict__ wvs, float* __restrict__ wvd) {
    int f = threadIdx.x;
    const float* row = W + f * 128;
    float s = 0.f, d = 0.f;
    #pragma unroll 8
    for (int j = 0; j < 128; ++j) {
        float w = row[j];
        s += w * att_src[j];
        d += w * att_dst[j];
    }
    wvs[f] = s; wvd[f] = d;
}

// Per-node logits + precomputed tables:
//   espair[n] = {e^{a_s}, e^{0.2 a_s}}   (pass-1 src operand, one b64 read)
//   wtab[n]   = e^{-a_d}                 (pass-1 branch threshold: p > w)
//   a_d[n]                               (kA epilogue / k4b combine)
__global__ void k2_logits(const float* __restrict__ x1, const float* __restrict__ x2,
                          const float* __restrict__ wvs, const float* __restrict__ wvd,
                          float* __restrict__ a_d, float2* __restrict__ espair,
                          float* __restrict__ wtab) {
    int wave = blockIdx.x * 4 + (threadIdx.x >> 6);
    int lane = threadIdx.x & 63;
    const float* xrow = (wave < NNODES) ? (x1 + (size_t)wave * 256)
                                        : (x2 + (size_t)(wave - NNODES) * 256);
    float4 xv  = ((const float4*)xrow)[lane];
    float4 wsv = ((const float4*)wvs)[lane];
    float4 wdv = ((const float4*)wvd)[lane];
    float ps = xv.x*wsv.x + xv.y*wsv.y + xv.z*wsv.z + xv.w*wsv.w;
    float pd = xv.x*wdv.x + xv.y*wdv.y + xv.z*wdv.z + xv.w*wdv.w;
    #pragma unroll
    for (int o = 32; o > 0; o >>= 1) {
        ps += __shfl_down(ps, o);
        pd += __shfl_down(pd, o);
    }
    if (lane == 0) {
        a_d[wave]    = pd;
        espair[wave] = make_float2(__expf(ps), __expf(NEG_SLOPE * ps));
        wtab[wave]   = __expf(-pd);
    }
}

// Pass 1: stage tables -> barrier -> issue ALL 16 index loads -> process.
// Loads sit between the barrier and the first atomic, so the compiler can
// neither drain them (no barrier crossing) nor sink them (atomics below).
__global__ __launch_bounds__(EK_TPB, 4) void kA_denom(
        const int* __restrict__ ei1, const int* __restrict__ ei2,
        const float2* __restrict__ espair, const float* __restrict__ wtab,
        const float* __restrict__ a_d,
        float* __restrict__ partials, float* __restrict__ out,
        int E1, int g1_blocks) {
    __shared__ float2 les[NNODES];           // 32 KB {e^as, e^.2as}
    __shared__ float  lw[NNODES];            // 16 KB e^{-ad}
    __shared__ float  s12[2 * NNODES];       // 32 KB split sums (80 KB total)
    int t = threadIdx.x;
    int b = blockIdx.x;
    const int* sp; int qbase, nodeoff, outq;
    if (b < g1_blocks) { sp = ei1; qbase = b * EK_QPB; nodeoff = 0; outq = qbase; }
    else { sp = ei2; qbase = (b - g1_blocks) * EK_QPB; nodeoff = NNODES; outq = E1/4 + qbase; }
    const int4* s4 = (const int4*)sp;
    const int4* d4 = (const int4*)(sp + E1);

    {   // stage tables: les = 2048 float4, lw = 1024 float4, s12 = 2048 float4
        float4* lesv = (float4*)les;
        const float4* gesv = (const float4*)(espair + nodeoff);
        lesv[t] = gesv[t]; lesv[t + 1024] = gesv[t + 1024];
        ((float4*)lw)[t] = ((const float4*)(wtab + nodeoff))[t];
        float4* zv = (float4*)s12;
        zv[t] = make_float4(0.f,0.f,0.f,0.f);
        zv[t + 1024] = make_float4(0.f,0.f,0.f,0.f);
    }
    __syncthreads();

    // ---- load phase (post-barrier): all 16 int4 loads in flight ----
    int4 sv[8], dv[8];
    #pragma unroll
    for (int k = 0; k < 8; ++k) {
        int q = qbase + (k << 10) + t;
        sv[k] = s4[q];
        dv[k] = d4[q];
    }

    // ---- process phase: fine-grained vmcnt waits, no drain ----
    float4* out4 = (float4*)out;
    #pragma unroll
    for (int k = 0; k < 8; ++k) {
        float2 e0 = les[sv[k].x], e1 = les[sv[k].y], e2 = les[sv[k].z], e3 = les[sv[k].w];
        float  w0 = lw[dv[k].x],  w1 = lw[dv[k].y],  w2 = lw[dv[k].z],  w3 = lw[dv[k].w];
        bool p0 = e0.x > w0, p1 = e1.x > w1, p2 = e2.x > w2, p3 = e3.x > w3;
        atomicAdd(&s12[dv[k].x + (p0 ? 0 : NNODES)], p0 ? e0.x : e0.y);
        atomicAdd(&s12[dv[k].y + (p1 ? 0 : NNODES)], p1 ? e1.x : e1.y);
        atomicAdd(&s12[dv[k].z + (p2 ? 0 : NNODES)], p2 ? e2.x : e2.y);
        atomicAdd(&s12[dv[k].w + (p3 ? 0 : NNODES)], p3 ? e3.x : e3.y);
        out4[outq + (k << 10) + t] = make_float4(p0 ? e0.x : -e0.y,
                                                 p1 ? e1.x : -e1.y,
                                                 p2 ? e2.x : -e2.y,
                                                 p3 ? e3.x : -e3.y);
    }
    __syncthreads();

    // partial_denom[n] = e^{ad}*s1[n] + e^{0.2 ad}*s2[n]  (linear in s1,s2,
    // so per-block combine is exact); keeps partials at 8 MB total.
    float4 ad4 = ((const float4*)(a_d + nodeoff))[t];
    int n = 4 * t;
    float4 r;
    r.x = __expf(ad4.x) * s12[n+0] + __expf(NEG_SLOPE * ad4.x) * s12[n+0+NNODES];
    r.y = __expf(ad4.y) * s12[n+1] + __expf(NEG_SLOPE * ad4.y) * s12[n+1+NNODES];
    r.z = __expf(ad4.z) * s12[n+2] + __expf(NEG_SLOPE * ad4.z) * s12[n+2+NNODES];
    r.w = __expf(ad4.w) * s12[n+3] + __expf(NEG_SLOPE * ad4.w) * s12[n+3+NNODES];
    ((float4*)(partials + (size_t)b * NNODES))[t] = r;
}

// Column-sum of partials [512][4096] -> partials2 [32][8192].
// float4 columns, 32 chunks x 8 rows: 8 independent float4 loads in
// flight per thread, 65536 threads (full CU coverage).
__global__ void k4a_reduce(const float* __restrict__ partials,
                           float* __restrict__ partials2, int g1_blocks) {
    int tid = blockIdx.x * blockDim.x + threadIdx.x;   // 65536
    int cg = tid & 1023;            // float4 column-group within 4096 cols
    int c  = (tid >> 10) & 31;      // chunk
    int h  = tid >> 15;             // graph half
    int bpc = g1_blocks >> 5;       // 8 rows per chunk
    int b0 = h * g1_blocks + c * bpc;
    const float4* p4 = (const float4*)partials;
    float4 acc = make_float4(0.f, 0.f, 0.f, 0.f);
    #pragma unroll
    for (int j = 0; j < 8; ++j) {
        float4 v = p4[(size_t)(b0 + j) * 1024 + cg];
        acc.x += v.x; acc.y += v.y; acc.z += v.z; acc.w += v.w;
    }
    ((float4*)partials2)[c * 2048 + h * 1024 + cg] = acc;
}

__global__ void k4b_inv(const float* __restrict__ partials2,
                        const float* __restrict__ a_d,
                        float2* __restrict__ uv) {
    int sg = blockIdx.x * blockDim.x + threadIdx.x;
    float s = 0.f;
    #pragma unroll
    for (int c = 0; c < 32; ++c) s += partials2[c * NSEG + sg];
    float inv = 1.0f / s;
    float ad = a_d[sg];
    uv[sg] = make_float2(__expf(ad) * inv, __expf(NEG_SLOPE * ad) * inv);
}

// Pass 2: stage -> barrier -> load dv[8]+va[8] -> ONE ds_read_b64 per
// edge. val sign carries the pass-1 branch.
__global__ __launch_bounds__(EK_TPB, 4) void kB_alpha(
        const int* __restrict__ ei1, const int* __restrict__ ei2,
        const float2* __restrict__ uv,
        float* __restrict__ out, int E1, int g1_blocks) {
    __shared__ float2 luv[NNODES];           // 32 KB
    int t = threadIdx.x;
    int b = blockIdx.x;
    const int* sp; int qbase, outq;
    const float2* uvg;
    if (b < g1_blocks) { sp = ei1; qbase = b * EK_QPB; uvg = uv; outq = qbase; }
    else { sp = ei2; qbase = (b - g1_blocks) * EK_QPB; uvg = uv + NNODES; outq = E1/4 + qbase; }
    const int4* d4 = (const int4*)(sp + E1);
    float4* out4 = (float4*)out;

    float4* luvv = (float4*)luv;
    const float4* guv = (const float4*)uvg;
    luvv[t] = guv[t]; luvv[t + 1024] = guv[t + 1024];
    __syncthreads();

    // ---- load phase (post-barrier): 16 loads in flight ----
    int4   dv[8];
    float4 va[8];
    #pragma unroll
    for (int k = 0; k < 8; ++k) {
        int q = qbase + (k << 10) + t;
        dv[k] = d4[q];
        va[k] = out4[outq + (k << 10) + t];
    }

    #pragma unroll
    for (int k = 0; k < 8; ++k) {
        float2 u0 = luv[dv[k].x], u1 = luv[dv[k].y], u2 = luv[dv[k].z], u3 = luv[dv[k].w];
        float4 val = va[k];
        val.x = (val.x > 0.f) ? val.x * u0.x : (-val.x) * u0.y;
        val.y = (val.y > 0.f) ? val.y * u1.x : (-val.y) * u1.y;
        val.z = (val.z > 0.f) ? val.z * u2.x : (-val.z) * u2.y;
        val.w = (val.w > 0.f) ? val.w * u3.x : (-val.w) * u3.y;
        out4[outq + (k << 10) + t] = val;
    }
}

extern "C" void kernel_launch(void* const* d_in, const int* in_sizes, int n_in,
                              void* d_out, int out_size, void* d_ws, size_t ws_size,
                              hipStream_t stream) {
    const float* x1      = (const float*)d_in[0];
    const float* x2      = (const float*)d_in[1];
    const int*   ei1     = (const int*)d_in[2];
    const int*   ei2     = (const int*)d_in[3];
    const float* W       = (const float*)d_in[4];
    const float* att_src = (const float*)d_in[5];
    const float* att_dst = (const float*)d_in[6];
    float* out = (float*)d_out;

    const int E1 = in_sizes[2] / 2;          // 8388608 edges per graph

    float* wsf       = (float*)d_ws;
    float* wvs       = wsf;                  // 256
    float* wvd       = wsf + 256;            // 256
    float* a_d       = wsf + 512;            // 8192
    float2* espair   = (float2*)(wsf + 512 + NSEG);        // 8192 float2 (16384 f)
    float* wtab      = wsf + 512 + NSEG + 2*NSEG;          // 8192
    float2* uv       = (float2*)(wsf + 512 + 4*NSEG);      // 8192 float2 (16384 f)
    float* partials2 = wsf + 65536;          // 32*8192 = 262144 floats (1 MB)
    float* partials  = wsf + 393216;         // 512*4096 floats (8 MB)

    hipLaunchKernelGGL(k1_wvec, dim3(1), dim3(256), 0, stream,
                       W, att_src, att_dst, wvs, wvd);
    hipLaunchKernelGGL(k2_logits, dim3(2 * NNODES / 4), dim3(256), 0, stream,
                       x1, x2, wvs, wvd, a_d, espair, wtab);

    int g1b = (E1 / 4) / EK_QPB;             // 256 blocks per graph half
    hipLaunchKernelGGL(kA_denom, dim3(2 * g1b), dim3(EK_TPB), 0, stream,
                       ei1, ei2, espair, wtab, a_d, partials, out, E1, g1b);
    hipLaunchKernelGGL(k4a_reduce, dim3(256), dim3(256), 0, stream,
                       partials, partials2, g1b);
    hipLaunchKernelGGL(k4b_inv, dim3(NSEG / 256), dim3(256), 0, stream,
                       partials2, a_d, uv);
    hipLaunchKernelGGL(kB_alpha, dim3(2 * g1b), dim3(EK_TPB), 0, stream,
                       ei1, ei2, uv, out, E1, g1b);
}